// Round 14
// baseline (1060.649 us; speedup 1.0000x reference)
//
#include <hip/hip_runtime.h>

#define TLEN 512
#define HDIM 64
#define NB   8     // batches per block (cols 8-15 of MFMA duplicate 0-7)
#define NTH  512   // 8 waves: 0-3 layer0, 4-7 layer1
#define GRID 256   // 2048 / NB -> all 256 CUs busy
#define XPAD 740   // xs row stride

typedef __attribute__((ext_vector_type(8))) short bf16x8;
typedef __attribute__((ext_vector_type(4))) short short4v;
typedef __attribute__((ext_vector_type(4))) float f32x4;

__device__ __forceinline__ float sigm(float x){ return __fdividef(1.f, 1.f+__expf(-x)); }
__device__ __forceinline__ float tanh_(float x){ return 1.f - __fdividef(2.f, __expf(2.f*x)+1.f); }

// f32 -> bf16 round-to-nearest-even
__device__ __forceinline__ short bf16rn(float f){
    unsigned u = __float_as_uint(f);
    u = (u + 0x7FFFu + ((u >> 16) & 1u)) >> 16;
    return (short)u;
}
__device__ __forceinline__ float bf2f(short s){
    return __uint_as_float(((unsigned)(unsigned short)s) << 16);
}

// One 16-row x 64-k A-tile as hi/lo bf16 fragments for mfma_16x16x32.
// Lane l supplies A[rowbase + (l&15)][khalf*32 + (l>>4)*8 + e].  (verified r7/r12)
__device__ __forceinline__ void loadA(const float* __restrict__ W, int rowbase, int lane,
                                      bf16x8& hi0, bf16x8& lo0, bf16x8& hi1, bf16x8& lo1)
{
    const int row = rowbase + (lane & 15);
    const int q   = lane >> 4;
    const float* p = W + row * HDIM + q * 8;
    #pragma unroll
    for (int e = 0; e < 8; ++e) {
        const float f0 = p[e];
        const float f1 = p[32 + e];
        const short a0 = bf16rn(f0); hi0[e] = a0; lo0[e] = bf16rn(f0 - bf2f(a0));
        const short a1 = bf16rn(f1); hi1[e] = a1; lo1[e] = bf16rn(f1 - bf2f(a1));
    }
}

#define MFMA __builtin_amdgcn_mfma_f32_16x16x32_bf16

// __launch_bounds__ 2nd arg is CUDA-semantics MIN BLOCKS PER CU (measured:
// r5/r6 (768,3)->VGPR 56=2048/36; r12/r13 (512,2)->VGPR 128=2048/16).
// (NTH,1) -> 8 waves/CU -> 256-VGPR cap -> ~200-reg demand fits, no spill.
__global__ __launch_bounds__(NTH, 1)
void lstm2_ws(const float* __restrict__ x,
              const float* __restrict__ w_ih0,
              const float* __restrict__ w_hh0,
              const float* __restrict__ b_ih0,
              const float* __restrict__ b_hh0,
              const float* __restrict__ w_ih1,
              const float* __restrict__ w_hh1,
              const float* __restrict__ b_ih1,
              const float* __restrict__ b_hh1,
              const float* __restrict__ fc_w,
              const float* __restrict__ fc_b,
              float* __restrict__ out)
{
    // h fragment store: [buf][hi/lo][kh][q][batch][e]  (h[b][kh*32+q*8+e])
    // B-read (lane q,r15): &h?f[p][*][kh][q][r15][0] -> addr = lane*16B, conflict-free.
    __shared__ float xs[16 * XPAD];          // staged input (rows 8-15 duplicate 0-7)
    __shared__ short h1f[2][2][2][4][16][8]; // 16 KB
    __shared__ short h2f[2][2][2][4][16][8]; // 16 KB
    __shared__ float h2last[16][HDIM];       // 4 KB

    const int tid  = threadIdx.x;
    const int wid  = tid >> 6;
    const int lane = tid & 63;
    const int q    = lane >> 4;
    const int r15  = lane & 15;   // batch column (8-15 duplicate 0-7)
    const int b0   = blockIdx.x * NB;
    const bool isL0 = (wid < 4);

    // ---- stage x (coalesced float4); rows 8-15 duplicate rows 0-7 ----
    {
        const float4* xg = (const float4*)(x + (size_t)b0 * TLEN);
        for (int idx = tid; idx < 16 * TLEN / 4; idx += NTH) {
            const int row = idx >> 7;          // 0..15
            const int col = idx & 127;
            *(float4*)&xs[row * XPAD + col * 4] = xg[(row & 7) * 128 + col];
        }
    }
    // zero ALL of h1f/h2f (both buffers)
    for (int idx = tid; idx < 8192; idx += NTH) {
        ((short*)h1f)[idx] = 0;
        ((short*)h2f)[idx] = 0;
    }

    // ---- per-wave A fragments (divergent prolog, no barriers inside) ----
    const int w4 = isL0 ? wid : (wid - 4);
    const int U0 = w4 * 16;
    bf16x8 M0h0[4], M0l0[4], M0h1[4], M0l1[4];   // L0: w_hh0   | L1: w_ih1
    bf16x8 M1h0[4], M1l0[4], M1h1[4], M1l1[4];   // L0: unused  | L1: w_hh1
    f32x4 biasv[4], wih[4];
    if (isL0) {
        #pragma unroll
        for (int g = 0; g < 4; ++g)
            loadA(w_hh0, g * 64 + U0, lane, M0h0[g], M0l0[g], M0h1[g], M0l1[g]);
        #pragma unroll
        for (int g = 0; g < 4; ++g) {
            #pragma unroll
            for (int r = 0; r < 4; ++r) {
                const int row = g * 64 + U0 + q * 4 + r;
                biasv[g][r] = b_ih0[row] + b_hh0[row];
                wih[g][r]   = w_ih0[row];
            }
        }
    } else {
        #pragma unroll
        for (int g = 0; g < 4; ++g) {
            loadA(w_ih1, g * 64 + U0, lane, M0h0[g], M0l0[g], M0h1[g], M0l1[g]);
            loadA(w_hh1, g * 64 + U0, lane, M1h0[g], M1l0[g], M1h1[g], M1l1[g]);
        }
        #pragma unroll
        for (int g = 0; g < 4; ++g) {
            #pragma unroll
            for (int r = 0; r < 4; ++r) {
                const int row = g * 64 + U0 + q * 4 + r;
                biasv[g][r] = b_ih1[row] + b_hh1[row];
                wih[g][r]   = 0.f;
            }
        }
    }
    // h-write coords: unit u = U0 + 4q + r -> kh=(u>>5), qp=((u>>3)&3), eo=(q&1)*4
    const int kh = w4 >> 1;
    const int qp = (2 * w4 + (q >> 1)) & 3;
    const int eo = (q & 1) * 4;
    f32x4 cc = {0.f, 0.f, 0.f, 0.f};
    int p = 0;

    __syncthreads();   // staging + zeroed h visible to all

    // Skewed pipeline, barrier-uniform: iteration i -> L0 computes h1(i),
    // L1 computes h2(i-1). Single top-level barrier per iteration.
    for (int i = 0; i <= TLEN; ++i) {
        const bool active = isL0 ? (i < TLEN) : (i >= 1);
        if (active) {
            f32x4 acc[4];
            if (isL0) {
                const bf16x8 Bh0 = *(const bf16x8*)&h1f[p][0][0][q][r15][0];
                const bf16x8 Bh1 = *(const bf16x8*)&h1f[p][0][1][q][r15][0];
                const bf16x8 Bl0 = *(const bf16x8*)&h1f[p][1][0][q][r15][0];
                const bf16x8 Bl1 = *(const bf16x8*)&h1f[p][1][1][q][r15][0];
                const float xv = xs[r15 * XPAD + i];
                #pragma unroll
                for (int g = 0; g < 4; ++g) {
                    f32x4 a = biasv[g];
                    #pragma unroll
                    for (int r = 0; r < 4; ++r) a[r] = fmaf(wih[g][r], xv, a[r]);
                    a = MFMA(M0h0[g], Bh0, a, 0, 0, 0);
                    a = MFMA(M0h1[g], Bh1, a, 0, 0, 0);
                    a = MFMA(M0l0[g], Bh0, a, 0, 0, 0);
                    a = MFMA(M0l1[g], Bh1, a, 0, 0, 0);
                    a = MFMA(M0h0[g], Bl0, a, 0, 0, 0);
                    a = MFMA(M0h1[g], Bl1, a, 0, 0, 0);
                    acc[g] = a;
                }
            } else {
                const bf16x8 B1h0 = *(const bf16x8*)&h1f[p][0][0][q][r15][0];
                const bf16x8 B1h1 = *(const bf16x8*)&h1f[p][0][1][q][r15][0];
                const bf16x8 B1l0 = *(const bf16x8*)&h1f[p][1][0][q][r15][0];
                const bf16x8 B1l1 = *(const bf16x8*)&h1f[p][1][1][q][r15][0];
                const bf16x8 B2h0 = *(const bf16x8*)&h2f[p][0][0][q][r15][0];
                const bf16x8 B2h1 = *(const bf16x8*)&h2f[p][0][1][q][r15][0];
                const bf16x8 B2l0 = *(const bf16x8*)&h2f[p][1][0][q][r15][0];
                const bf16x8 B2l1 = *(const bf16x8*)&h2f[p][1][1][q][r15][0];
                #pragma unroll
                for (int g = 0; g < 4; ++g) {
                    f32x4 a = biasv[g];                       // w_ih1 . h1 chain
                    a = MFMA(M0h0[g], B1h0, a, 0, 0, 0);
                    a = MFMA(M0h1[g], B1h1, a, 0, 0, 0);
                    a = MFMA(M0l0[g], B1h0, a, 0, 0, 0);
                    a = MFMA(M0l1[g], B1h1, a, 0, 0, 0);
                    a = MFMA(M0h0[g], B1l0, a, 0, 0, 0);
                    a = MFMA(M0h1[g], B1l1, a, 0, 0, 0);
                    f32x4 h = {0.f, 0.f, 0.f, 0.f};           // w_hh1 . h2 chain (parallel)
                    h = MFMA(M1h0[g], B2h0, h, 0, 0, 0);
                    h = MFMA(M1h1[g], B2h1, h, 0, 0, 0);
                    h = MFMA(M1l0[g], B2h0, h, 0, 0, 0);
                    h = MFMA(M1l1[g], B2h1, h, 0, 0, 0);
                    h = MFMA(M1h0[g], B2l0, h, 0, 0, 0);
                    h = MFMA(M1h1[g], B2l1, h, 0, 0, 0);
                    #pragma unroll
                    for (int r = 0; r < 4; ++r) acc[g][r] = a[r] + h[r];
                }
            }
            // ---- in-register gate update ----
            float hv[4];
            #pragma unroll
            for (int r = 0; r < 4; ++r) {
                const float gi = sigm (acc[0][r]);
                const float gf = sigm (acc[1][r]);
                const float gg = tanh_(acc[2][r]);
                const float go = sigm (acc[3][r]);
                cc[r] = fmaf(gf, cc[r], gi * gg);
                hv[r] = go * tanh_(cc[r]);
            }
            const short hh0 = bf16rn(hv[0]), hl0 = bf16rn(hv[0] - bf2f(hh0));
            const short hh1 = bf16rn(hv[1]), hl1 = bf16rn(hv[1] - bf2f(hh1));
            const short hh2 = bf16rn(hv[2]), hl2 = bf16rn(hv[2] - bf2f(hh2));
            const short hh3 = bf16rn(hv[3]), hl3 = bf16rn(hv[3] - bf2f(hh3));
            if (isL0) {
                *(short4v*)&h1f[p ^ 1][0][kh][qp][r15][eo] = (short4v){hh0, hh1, hh2, hh3};
                *(short4v*)&h1f[p ^ 1][1][kh][qp][r15][eo] = (short4v){hl0, hl1, hl2, hl3};
            } else {
                *(short4v*)&h2f[p ^ 1][0][kh][qp][r15][eo] = (short4v){hh0, hh1, hh2, hh3};
                *(short4v*)&h2f[p ^ 1][1][kh][qp][r15][eo] = (short4v){hl0, hl1, hl2, hl3};
                if (i == TLEN)
                    *(f32x4*)&h2last[r15][U0 + q * 4] = (f32x4){hv[0], hv[1], hv[2], hv[3]};
            }
        }
        __syncthreads();   // uniform: every wave, every iteration
        p ^= 1;
    }

    // ======== final FC: thread (b = tid>>5, s = tid&31), batches 0..7 only ========
    {
        const int fb = tid >> 5, fs = tid & 31;   // fb 0..15; 8-15 are duplicates
        float psum = fc_w[fs] * h2last[fb][fs] + fc_w[fs + 32] * h2last[fb][fs + 32];
        psum += __shfl_xor(psum, 16);
        psum += __shfl_xor(psum, 8);
        psum += __shfl_xor(psum, 4);
        psum += __shfl_xor(psum, 2);
        psum += __shfl_xor(psum, 1);
        if (fs == 0 && fb < NB) out[b0 + fb] = psum + fc_b[0];
    }
}

extern "C" void kernel_launch(void* const* d_in, const int* in_sizes, int n_in,
                              void* d_out, int out_size, void* d_ws, size_t ws_size,
                              hipStream_t stream) {
    const float* xp     = (const float*)d_in[0];
    const float* w_ih0  = (const float*)d_in[1];
    const float* w_hh0  = (const float*)d_in[2];
    const float* b_ih0  = (const float*)d_in[3];
    const float* b_hh0  = (const float*)d_in[4];
    const float* w_ih1  = (const float*)d_in[5];
    const float* w_hh1  = (const float*)d_in[6];
    const float* b_ih1  = (const float*)d_in[7];
    const float* b_hh1  = (const float*)d_in[8];
    const float* fc_w   = (const float*)d_in[9];
    const float* fc_b   = (const float*)d_in[10];
    float* outp = (float*)d_out;

    lstm2_ws<<<dim3(GRID), dim3(NTH), 0, stream>>>(
        xp, w_ih0, w_hh0, b_ih0, b_hh0,
        w_ih1, w_hh1, b_ih1, b_hh1, fc_w, fc_b, outp);
}

// Round 15
// 872.825 us; speedup vs baseline: 1.2152x; 1.2152x over previous
//
#include <hip/hip_runtime.h>

#define TLEN 512
#define HDIM 64
#define NB   8     // real batches per block (MFMA cols 8-15 duplicate 0-7)
#define NTH  512   // 8 waves: 0-3 layer0, 4-7 layer1
#define GRID 256   // all 256 CUs busy
#define XPAD 516   // xs row stride (16B-aligned rows; 2-way bank alias only)

typedef __attribute__((ext_vector_type(8))) short bf16x8;
typedef __attribute__((ext_vector_type(4))) float f32x4;

__device__ __forceinline__ float sigm(float x){ return __fdividef(1.f, 1.f+__expf(-x)); }
__device__ __forceinline__ float tanh_(float x){ return 1.f - __fdividef(2.f, __expf(2.f*x)+1.f); }

__device__ __forceinline__ short bf16rn(float f){
    unsigned u = __float_as_uint(f);
    u = (u + 0x7FFFu + ((u >> 16) & 1u)) >> 16;
    return (short)u;
}
__device__ __forceinline__ float bf2f(short s){
    return __uint_as_float(((unsigned)(unsigned short)s) << 16);
}
__device__ __forceinline__ float bf2f_u(unsigned lo16){
    return __uint_as_float(lo16 << 16);
}

// One 16-row x 64-k A-tile as hi/lo bf16 fragments for mfma_16x16x32.
// Lane l supplies A[rowbase + (l&15)][khalf*32 + (l>>4)*8 + e].  (verified r7/r12)
__device__ __forceinline__ void loadA(const float* __restrict__ W, int rowbase, int lane,
                                      bf16x8& hi0, bf16x8& lo0, bf16x8& hi1, bf16x8& lo1)
{
    const int row = rowbase + (lane & 15);
    const int q   = lane >> 4;
    const float* p = W + row * HDIM + q * 8;
    #pragma unroll
    for (int e = 0; e < 8; ++e) {
        const float f0 = p[e];
        const float f1 = p[32 + e];
        const short a0 = bf16rn(f0); hi0[e] = a0; lo0[e] = bf16rn(f0 - bf2f(a0));
        const short a1 = bf16rn(f1); hi1[e] = a1; lo1[e] = bf16rn(f1 - bf2f(a1));
    }
}

#define MFMA __builtin_amdgcn_mfma_f32_16x16x32_bf16

// waves_per_eu(2,2): allocator budget = 512-reg pool / 2 = 256 VGPR (demand ~210,
// no spill). launch_bounds min-arg alone left the allocator at its 4-waves/EU
// default target -> VGPR=128 + L2-resident scratch churn (r12-r14 disease).
__global__ __launch_bounds__(NTH)
__attribute__((amdgpu_waves_per_eu(2, 2)))
void lstm2_ws(const float* __restrict__ x,
              const float* __restrict__ w_ih0,
              const float* __restrict__ w_hh0,
              const float* __restrict__ b_ih0,
              const float* __restrict__ b_hh0,
              const float* __restrict__ w_ih1,
              const float* __restrict__ w_hh1,
              const float* __restrict__ b_ih1,
              const float* __restrict__ b_hh1,
              const float* __restrict__ fc_w,
              const float* __restrict__ fc_b,
              float* __restrict__ out)
{
    // h fragment store: [buf][hi/lo][kh][q][batch][e]  (h[b][kh*32+q*8+e])
    // B-read (lane q,r15): addr = lane*16B -> conflict-free b128.
    __shared__ float xs[16 * XPAD];          // 33 KB (rows 8-15 duplicate 0-7)
    __shared__ short h1f[2][2][2][4][16][8]; // 16 KB
    __shared__ short h2f[2][2][2][4][16][8]; // 16 KB
    __shared__ float h2last[16][HDIM];       // 4 KB

    const int tid  = threadIdx.x;
    const int wid  = tid >> 6;
    const int lane = tid & 63;
    const int q    = lane >> 4;
    const int r15  = lane & 15;   // batch column (8-15 duplicate 0-7)
    const int b0   = blockIdx.x * NB;
    const bool isL0   = (wid < 4);
    const bool lohalf = (r15 < 8);

    // ---- stage x (coalesced float4); rows 8-15 duplicate rows 0-7 ----
    {
        const float4* xg = (const float4*)(x + (size_t)b0 * TLEN);
        for (int idx = tid; idx < 16 * TLEN / 4; idx += NTH) {
            const int row = idx >> 7;          // 0..15
            const int col = idx & 127;
            *(float4*)&xs[row * XPAD + col * 4] = xg[(row & 7) * 128 + col];
        }
    }
    // zero ALL of h1f/h2f (both buffers)
    for (int idx = tid; idx < 8192; idx += NTH) {
        ((short*)h1f)[idx] = 0;
        ((short*)h2f)[idx] = 0;
    }

    // ---- per-wave A fragments (divergent prolog, no barriers inside) ----
    const int w4 = isL0 ? wid : (wid - 4);
    const int U0 = w4 * 16;
    bf16x8 M0h0[4], M0l0[4], M0h1[4], M0l1[4];   // L0: w_hh0   | L1: w_ih1
    bf16x8 M1h0[4], M1l0[4], M1h1[4], M1l1[4];   // L0: unused  | L1: w_hh1
    f32x4 biasv[4], wih[4];
    if (isL0) {
        #pragma unroll
        for (int g = 0; g < 4; ++g)
            loadA(w_hh0, g * 64 + U0, lane, M0h0[g], M0l0[g], M0h1[g], M0l1[g]);
        #pragma unroll
        for (int g = 0; g < 4; ++g) {
            #pragma unroll
            for (int r = 0; r < 4; ++r) {
                const int row = g * 64 + U0 + q * 4 + r;
                biasv[g][r] = b_ih0[row] + b_hh0[row];
                wih[g][r]   = w_ih0[row];
            }
        }
    } else {
        #pragma unroll
        for (int g = 0; g < 4; ++g) {
            loadA(w_ih1, g * 64 + U0, lane, M0h0[g], M0l0[g], M0h1[g], M0l1[g]);
            loadA(w_hh1, g * 64 + U0, lane, M1h0[g], M1l0[g], M1h1[g], M1l1[g]);
        }
        #pragma unroll
        for (int g = 0; g < 4; ++g) {
            #pragma unroll
            for (int r = 0; r < 4; ++r) {
                const int row = g * 64 + U0 + q * 4 + r;
                biasv[g][r] = b_ih1[row] + b_hh1[row];
                wih[g][r]   = 0.f;
            }
        }
    }
    // h-write coords: unit u = U0 + 4q + r -> kh=(u>>5), qp=((u>>3)&3), eo=(q&1)*4
    const int kh = w4 >> 1;
    const int qp = (2 * w4 + (q >> 1)) & 3;
    const int eo = (q & 1) * 4;
    // each lane owns TWO cell states: lohalf -> (r0,r1), else (r2,r3); partner
    // lane (lane^8) holds the other pair (cols r15 and r15^8 are bit-identical).
    float ccA = 0.f, ccB = 0.f;
    int p = 0;

    __syncthreads();   // staging + zeroed h visible to all

    // Skewed pipeline, barrier-uniform: iteration i -> L0 computes h1(i),
    // L1 computes h2(i-1). Single top-level barrier per iteration.
    for (int i = 0; i <= TLEN; ++i) {
        const bool active = isL0 ? (i < TLEN) : (i >= 1);
        if (active) {
            f32x4 acc[4];
            if (isL0) {
                const bf16x8 Bh0 = *(const bf16x8*)&h1f[p][0][0][q][r15][0];
                const bf16x8 Bh1 = *(const bf16x8*)&h1f[p][0][1][q][r15][0];
                const bf16x8 Bl0 = *(const bf16x8*)&h1f[p][1][0][q][r15][0];
                const bf16x8 Bl1 = *(const bf16x8*)&h1f[p][1][1][q][r15][0];
                const float xv = xs[r15 * XPAD + i];
                #pragma unroll
                for (int g = 0; g < 4; ++g) {
                    f32x4 a = biasv[g];
                    #pragma unroll
                    for (int r = 0; r < 4; ++r) a[r] = fmaf(wih[g][r], xv, a[r]);
                    a = MFMA(M0h0[g], Bh0, a, 0, 0, 0);     // chain A (3-deep)
                    a = MFMA(M0l0[g], Bh0, a, 0, 0, 0);
                    a = MFMA(M0h0[g], Bl0, a, 0, 0, 0);
                    f32x4 b2 = {0.f, 0.f, 0.f, 0.f};        // chain B (3-deep)
                    b2 = MFMA(M0h1[g], Bh1, b2, 0, 0, 0);
                    b2 = MFMA(M0l1[g], Bh1, b2, 0, 0, 0);
                    b2 = MFMA(M0h1[g], Bl1, b2, 0, 0, 0);
                    #pragma unroll
                    for (int r = 0; r < 4; ++r) acc[g][r] = a[r] + b2[r];
                }
            } else {
                const bf16x8 B1h0 = *(const bf16x8*)&h1f[p][0][0][q][r15][0];
                const bf16x8 B1h1 = *(const bf16x8*)&h1f[p][0][1][q][r15][0];
                const bf16x8 B1l0 = *(const bf16x8*)&h1f[p][1][0][q][r15][0];
                const bf16x8 B1l1 = *(const bf16x8*)&h1f[p][1][1][q][r15][0];
                const bf16x8 B2h0 = *(const bf16x8*)&h2f[p][0][0][q][r15][0];
                const bf16x8 B2h1 = *(const bf16x8*)&h2f[p][0][1][q][r15][0];
                const bf16x8 B2l0 = *(const bf16x8*)&h2f[p][1][0][q][r15][0];
                const bf16x8 B2l1 = *(const bf16x8*)&h2f[p][1][1][q][r15][0];
                #pragma unroll
                for (int g = 0; g < 4; ++g) {
                    f32x4 a = biasv[g];                       // w_ih1 . h1 chain
                    a = MFMA(M0h0[g], B1h0, a, 0, 0, 0);
                    a = MFMA(M0h1[g], B1h1, a, 0, 0, 0);
                    a = MFMA(M0l0[g], B1h0, a, 0, 0, 0);
                    a = MFMA(M0l1[g], B1h1, a, 0, 0, 0);
                    a = MFMA(M0h0[g], B1l0, a, 0, 0, 0);
                    a = MFMA(M0h1[g], B1l1, a, 0, 0, 0);
                    f32x4 h = {0.f, 0.f, 0.f, 0.f};           // w_hh1 . h2 chain
                    h = MFMA(M1h0[g], B2h0, h, 0, 0, 0);
                    h = MFMA(M1h1[g], B2h1, h, 0, 0, 0);
                    h = MFMA(M1l0[g], B2h0, h, 0, 0, 0);
                    h = MFMA(M1l1[g], B2h1, h, 0, 0, 0);
                    h = MFMA(M1h0[g], B2l0, h, 0, 0, 0);
                    h = MFMA(M1h1[g], B2l1, h, 0, 0, 0);
                    #pragma unroll
                    for (int r = 0; r < 4; ++r) acc[g][r] = a[r] + h[r];
                }
            }
            // ---- in-register gate update: 2 r-values per lane, partner has other 2 ----
            float a0g[4], a1g[4];
            #pragma unroll
            for (int g = 0; g < 4; ++g) {
                a0g[g] = lohalf ? acc[g][0] : acc[g][2];
                a1g[g] = lohalf ? acc[g][1] : acc[g][3];
            }
            float hvA, hvB;
            {
                const float gi = sigm(a0g[0]), gf = sigm(a0g[1]);
                const float gg = tanh_(a0g[2]), go = sigm(a0g[3]);
                ccA = fmaf(gf, ccA, gi * gg);
                hvA = go * tanh_(ccA);
            }
            {
                const float gi = sigm(a1g[0]), gf = sigm(a1g[1]);
                const float gg = tanh_(a1g[2]), go = sigm(a1g[3]);
                ccB = fmaf(gf, ccB, gi * gg);
                hvB = go * tanh_(ccB);
            }
            const short sA = bf16rn(hvA), lA = bf16rn(hvA - bf2f(sA));
            const short sB = bf16rn(hvB), lB = bf16rn(hvB - bf2f(sB));
            const unsigned ownH = (unsigned)(unsigned short)sA | ((unsigned)(unsigned short)sB << 16);
            const unsigned ownL = (unsigned)(unsigned short)lA | ((unsigned)(unsigned short)lB << 16);
            const unsigned othH = (unsigned)__shfl_xor((int)ownH, 8, 64);
            const unsigned othL = (unsigned)__shfl_xor((int)ownL, 8, 64);
            const unsigned h01 = lohalf ? ownH : othH;   // (r0,r1) bf16 hi pair
            const unsigned h23 = lohalf ? othH : ownH;   // (r2,r3)
            const unsigned l01 = lohalf ? ownL : othL;
            const unsigned l23 = lohalf ? othL : ownL;
            if (isL0) {
                *(uint2*)&h1f[p ^ 1][0][kh][qp][r15][eo] = (uint2){h01, h23};
                *(uint2*)&h1f[p ^ 1][1][kh][qp][r15][eo] = (uint2){l01, l23};
            } else {
                *(uint2*)&h2f[p ^ 1][0][kh][qp][r15][eo] = (uint2){h01, h23};
                *(uint2*)&h2f[p ^ 1][1][kh][qp][r15][eo] = (uint2){l01, l23};
                if (i == TLEN) {
                    // reconstruct all 4 f32 (hi+lo double-bf16, err ~2^-17)
                    f32x4 hv;
                    hv[0] = bf2f_u(h01 & 0xFFFFu) + bf2f_u(l01 & 0xFFFFu);
                    hv[1] = bf2f_u(h01 >> 16)     + bf2f_u(l01 >> 16);
                    hv[2] = bf2f_u(h23 & 0xFFFFu) + bf2f_u(l23 & 0xFFFFu);
                    hv[3] = bf2f_u(h23 >> 16)     + bf2f_u(l23 >> 16);
                    *(f32x4*)&h2last[r15][U0 + q * 4] = hv;
                }
            }
        }
        __syncthreads();   // uniform: every wave, every iteration
        p ^= 1;
    }

    // ======== final FC: thread (b = tid>>5, s = tid&31), batches 0..7 only ========
    {
        const int fb = tid >> 5, fs = tid & 31;   // fb 0..15; 8-15 are duplicates
        float psum = fc_w[fs] * h2last[fb][fs] + fc_w[fs + 32] * h2last[fb][fs + 32];
        psum += __shfl_xor(psum, 16);
        psum += __shfl_xor(psum, 8);
        psum += __shfl_xor(psum, 4);
        psum += __shfl_xor(psum, 2);
        psum += __shfl_xor(psum, 1);
        if (fs == 0 && fb < NB) out[b0 + fb] = psum + fc_b[0];
    }
}

extern "C" void kernel_launch(void* const* d_in, const int* in_sizes, int n_in,
                              void* d_out, int out_size, void* d_ws, size_t ws_size,
                              hipStream_t stream) {
    const float* xp     = (const float*)d_in[0];
    const float* w_ih0  = (const float*)d_in[1];
    const float* w_hh0  = (const float*)d_in[2];
    const float* b_ih0  = (const float*)d_in[3];
    const float* b_hh0  = (const float*)d_in[4];
    const float* w_ih1  = (const float*)d_in[5];
    const float* w_hh1  = (const float*)d_in[6];
    const float* b_ih1  = (const float*)d_in[7];
    const float* b_hh1  = (const float*)d_in[8];
    const float* fc_w   = (const float*)d_in[9];
    const float* fc_b   = (const float*)d_in[10];
    float* outp = (float*)d_out;

    lstm2_ws<<<dim3(GRID), dim3(NTH), 0, stream>>>(
        xp, w_ih0, w_hh0, b_ih0, b_hh0,
        w_ih1, w_hh1, b_ih1, b_hh1, fc_w, fc_b, outp);
}